// Round 1
// baseline (1083.712 us; speedup 1.0000x reference)
//
#include <hip/hip_runtime.h>

#define B_    32
#define NW_   64
#define BW_   2048   // B*NW
#define L_    49
#define D_    192
#define PROJ_ 256
#define H_    8
#define HD_   32

// ---------------------------------------------------------------------------
// Projection: out[bw,h,l,hd] = sum_k x[bw*49+l, k] * W[k, h*32+hd] + bias
// grid (BW_, 3) : blockIdx.y selects (q / k / v). block = 256 threads.
// Thread layout: tx = tid&31 (cols {tx*4, 128+tx*4}), ty = tid>>5 (rows ty*8..+7)
// ---------------------------------------------------------------------------
__global__ __launch_bounds__(256) void proj_kernel(
    const float* __restrict__ query, const float* __restrict__ key_,
    const float* __restrict__ value,
    const float* __restrict__ Wq, const float* __restrict__ bq,
    const float* __restrict__ Wk, const float* __restrict__ bk,
    const float* __restrict__ Wv,
    float* __restrict__ qp, float* __restrict__ kp, float* __restrict__ vp)
{
    const int bw  = blockIdx.x;
    const int sel = blockIdx.y;
    const float* x; const float* W; const float* bias; float* outp;
    if (sel == 0)      { x = query; W = Wq; bias = bq;      outp = qp; }
    else if (sel == 1) { x = key_;  W = Wk; bias = bk;      outp = kp; }
    else               { x = value; W = Wv; bias = nullptr; outp = vp; }

    __shared__ __align__(16) float xsT[32][68];   // [k][l], pad 68 (16B-aligned rows)
    __shared__ __align__(16) float wS[32][PROJ_]; // [k][n]

    const int tid = threadIdx.x;
    const int tx  = tid & 31;
    const int ty  = tid >> 5;

    float acc[8][8];
    #pragma unroll
    for (int r = 0; r < 8; ++r)
        #pragma unroll
        for (int c = 0; c < 8; ++c) acc[r][c] = 0.f;

    for (int k0 = 0; k0 < D_; k0 += 32) {
        __syncthreads();
        // stage x-tile transposed: 49 rows x 32 k
        for (int idx = tid; idx < L_ * 32; idx += 256) {
            int l = idx >> 5, k = idx & 31;
            xsT[k][l] = x[(bw * L_ + l) * D_ + k0 + k];
        }
        // stage W-tile: 32 k x 256 n, float4
        for (int idx = tid; idx < 32 * 64; idx += 256) {
            int k = idx >> 6, g = idx & 63;
            *(float4*)&wS[k][g * 4] = *(const float4*)&W[(k0 + k) * PROJ_ + g * 4];
        }
        __syncthreads();
        #pragma unroll 4
        for (int kk = 0; kk < 32; ++kk) {
            float4 a0 = *(const float4*)&xsT[kk][ty * 8];
            float4 a1 = *(const float4*)&xsT[kk][ty * 8 + 4];
            float4 b0 = *(const float4*)&wS[kk][tx * 4];
            float4 b1 = *(const float4*)&wS[kk][128 + tx * 4];
            float a[8] = {a0.x,a0.y,a0.z,a0.w,a1.x,a1.y,a1.z,a1.w};
            float b[8] = {b0.x,b0.y,b0.z,b0.w,b1.x,b1.y,b1.z,b1.w};
            #pragma unroll
            for (int r = 0; r < 8; ++r)
                #pragma unroll
                for (int c = 0; c < 8; ++c)
                    acc[r][c] += a[r] * b[c];
        }
    }

    #pragma unroll
    for (int j4 = 0; j4 < 2; ++j4) {
        int n  = j4 * 128 + tx * 4;
        int h  = n >> 5, hd = n & 31;
        float4 bv = make_float4(0.f, 0.f, 0.f, 0.f);
        if (bias) bv = *(const float4*)&bias[n];
        #pragma unroll
        for (int r = 0; r < 8; ++r) {
            int l = ty * 8 + r;
            if (l < L_) {
                float4 o;
                o.x = acc[r][j4 * 4 + 0] + bv.x;
                o.y = acc[r][j4 * 4 + 1] + bv.y;
                o.z = acc[r][j4 * 4 + 2] + bv.z;
                o.w = acc[r][j4 * 4 + 3] + bv.w;
                *(float4*)&outp[((bw * H_ + h) * L_ + l) * HD_ + hd] = o;
            }
        }
    }
}

// ---------------------------------------------------------------------------
// Attention: one wave (64 threads) per (bw, head). 16384 blocks.
// S = (q k^T) * scale, mask -> -1000, softmax rows, O = P v.
// O overwrites qp (same [bw,h,l,hd] slot; block-disjoint, read-before-write).
// ---------------------------------------------------------------------------
__global__ __launch_bounds__(64) void attn_kernel(
    const float* qp_in, const float* __restrict__ kp,
    const float* __restrict__ vp, const int* __restrict__ mask,
    float* op)
{
    const int bh   = blockIdx.x;       // bw*8 + h
    const int bw   = bh >> 3;
    const int w    = bw & (NW_ - 1);   // window index for mask
    const int lane = threadIdx.x;
    const int ty   = lane >> 3;        // 0..7
    const int tx   = lane & 7;         // 0..7

    __shared__ __align__(16) float smem[64 * 68];  // qsT[32][68]+ksT[32][68], later PsT[64][68]
    __shared__ __align__(16) float vs[L_][32];     // [j][c]
    __shared__ float inv_l[64];

    float (*qsT)[68] = (float (*)[68])smem;
    float (*ksT)[68] = (float (*)[68])(smem + 32 * 68);
    float (*PsT)[68] = (float (*)[68])smem;

    const float* qb = qp_in + (size_t)bh * (L_ * HD_);
    const float* kb = kp    + (size_t)bh * (L_ * HD_);
    const float* vb = vp    + (size_t)bh * (L_ * HD_);

    // stage q,k transposed [c][l]; v natural [j][c]
    for (int idx = lane; idx < L_ * 32; idx += 64) {
        int l = idx >> 5, c = idx & 31;
        qsT[c][l] = qb[idx];
        ksT[c][l] = kb[idx];
    }
    for (int i4 = lane; i4 < L_ * 8; i4 += 64)
        ((float4*)vs)[i4] = ((const float4*)vb)[i4];
    __syncthreads();

    // scores: 64x64 padded tile, 8x8 per lane, K=32
    float sacc[8][8];
    #pragma unroll
    for (int r = 0; r < 8; ++r)
        #pragma unroll
        for (int c = 0; c < 8; ++c) sacc[r][c] = 0.f;

    #pragma unroll 4
    for (int kk = 0; kk < 32; ++kk) {
        float4 a0 = *(const float4*)&qsT[kk][ty * 8];
        float4 a1 = *(const float4*)&qsT[kk][ty * 8 + 4];
        float4 b0 = *(const float4*)&ksT[kk][tx * 8];
        float4 b1 = *(const float4*)&ksT[kk][tx * 8 + 4];
        float a[8] = {a0.x,a0.y,a0.z,a0.w,a1.x,a1.y,a1.z,a1.w};
        float b[8] = {b0.x,b0.y,b0.z,b0.w,b1.x,b1.y,b1.z,b1.w};
        #pragma unroll
        for (int r = 0; r < 8; ++r)
            #pragma unroll
            for (int c = 0; c < 8; ++c)
                sacc[r][c] += a[r] * b[c];
    }
    __syncthreads();   // all qsT/ksT reads done before PsT overwrites them

    const float scale = 0.17677669529663687f;  // 1/sqrt(32)
    #pragma unroll
    for (int r = 0; r < 8; ++r) {
        int i = ty * 8 + r;
        #pragma unroll
        for (int c = 0; c < 8; ++c) {
            int j = tx * 8 + c;
            if (i < L_ && j < L_) {
                float s = sacc[r][c] * scale;
                if (mask[w * (L_ * L_) + i * L_ + j] != 0) s = -1000.f;
                PsT[j][i] = s;   // store transposed for PV A-operand
            }
        }
    }
    __syncthreads();

    // softmax over j per row i (one lane per row)
    if (lane < L_) {
        float m = -3.0e38f;
        for (int j = 0; j < L_; ++j) m = fmaxf(m, PsT[j][lane]);
        float sum = 0.f;
        for (int j = 0; j < L_; ++j) {
            float e = __expf(PsT[j][lane] - m);
            PsT[j][lane] = e;
            sum += e;
        }
        inv_l[lane] = 1.0f / sum;
    }
    __syncthreads();

    // O = P v : K=49, 8 rows x 4 cols per lane (ty rows, tx cols)
    float oacc[8][4];
    #pragma unroll
    for (int r = 0; r < 8; ++r)
        #pragma unroll
        for (int c = 0; c < 4; ++c) oacc[r][c] = 0.f;

    for (int kk = 0; kk < L_; ++kk) {
        float4 a0 = *(const float4*)&PsT[kk][ty * 8];
        float4 a1 = *(const float4*)&PsT[kk][ty * 8 + 4];
        float4 b  = *(const float4*)&vs[kk][tx * 4];
        float a[8] = {a0.x,a0.y,a0.z,a0.w,a1.x,a1.y,a1.z,a1.w};
        float bb[4] = {b.x,b.y,b.z,b.w};
        #pragma unroll
        for (int r = 0; r < 8; ++r)
            #pragma unroll
            for (int c = 0; c < 4; ++c)
                oacc[r][c] += a[r] * bb[c];
    }

    #pragma unroll
    for (int r = 0; r < 8; ++r) {
        int i = ty * 8 + r;
        if (i < L_) {
            float iv = inv_l[i];
            float4 o;
            o.x = oacc[r][0] * iv;
            o.y = oacc[r][1] * iv;
            o.z = oacc[r][2] * iv;
            o.w = oacc[r][3] * iv;
            *(float4*)&op[(size_t)bh * (L_ * HD_) + i * 32 + tx * 4] = o;
        }
    }
}

// ---------------------------------------------------------------------------
// Output projection: out[bw*49+l, c] = sum_p o[bw,h(p),l,hd(p)] * Ww[p,c] + bw
// grid BW_, block 256: ty=tid>>5 rows ty*8..+7; tx=tid&31 cols {tx*4, 128+tx*2}
// ---------------------------------------------------------------------------
__global__ __launch_bounds__(256) void outproj_kernel(
    const float* __restrict__ op, const float* __restrict__ Ww,
    const float* __restrict__ bw_, float* __restrict__ out)
{
    const int bw  = blockIdx.x;
    const int tid = threadIdx.x;
    const int tx  = tid & 31;
    const int ty  = tid >> 5;

    __shared__ __align__(16) float osT[32][68];
    __shared__ __align__(16) float wS[32][D_];

    float acc[8][6];
    #pragma unroll
    for (int r = 0; r < 8; ++r)
        #pragma unroll
        for (int c = 0; c < 6; ++c) acc[r][c] = 0.f;

    for (int k0 = 0; k0 < PROJ_; k0 += 32) {
        const int hsel = k0 >> 5;
        __syncthreads();
        for (int idx = tid; idx < L_ * 32; idx += 256) {
            int l = idx >> 5, k = idx & 31;
            osT[k][l] = op[((bw * H_ + hsel) * L_ + l) * HD_ + k];
        }
        for (int i4 = tid; i4 < 32 * 48; i4 += 256) {
            int k = i4 / 48, g = i4 - k * 48;
            *(float4*)&wS[k][g * 4] = *(const float4*)&Ww[(k0 + k) * D_ + g * 4];
        }
        __syncthreads();
        #pragma unroll 4
        for (int kk = 0; kk < 32; ++kk) {
            float4 a0 = *(const float4*)&osT[kk][ty * 8];
            float4 a1 = *(const float4*)&osT[kk][ty * 8 + 4];
            float4 b0 = *(const float4*)&wS[kk][tx * 4];
            float2 b1 = *(const float2*)&wS[kk][128 + tx * 2];
            float a[8] = {a0.x,a0.y,a0.z,a0.w,a1.x,a1.y,a1.z,a1.w};
            float b[6] = {b0.x,b0.y,b0.z,b0.w,b1.x,b1.y};
            #pragma unroll
            for (int r = 0; r < 8; ++r)
                #pragma unroll
                for (int c = 0; c < 6; ++c)
                    acc[r][c] += a[r] * b[c];
        }
    }

    float4 bv0 = *(const float4*)&bw_[tx * 4];
    float2 bv1 = *(const float2*)&bw_[128 + tx * 2];
    #pragma unroll
    for (int r = 0; r < 8; ++r) {
        int l = ty * 8 + r;
        if (l < L_) {
            float4 o;
            o.x = acc[r][0] + bv0.x;
            o.y = acc[r][1] + bv0.y;
            o.z = acc[r][2] + bv0.z;
            o.w = acc[r][3] + bv0.w;
            *(float4*)&out[(bw * L_ + l) * D_ + tx * 4] = o;
            float2 o2;
            o2.x = acc[r][4] + bv1.x;
            o2.y = acc[r][5] + bv1.y;
            *(float2*)&out[(bw * L_ + l) * D_ + 128 + tx * 2] = o2;
        }
    }
}

extern "C" void kernel_launch(void* const* d_in, const int* in_sizes, int n_in,
                              void* d_out, int out_size, void* d_ws, size_t ws_size,
                              hipStream_t stream) {
    const float* query = (const float*)d_in[0];
    const float* key_  = (const float*)d_in[1];
    const float* value = (const float*)d_in[2];
    const int*   mask  = (const int*)d_in[3];
    const float* Wq    = (const float*)d_in[4];
    const float* bq    = (const float*)d_in[5];
    const float* Wk    = (const float*)d_in[6];
    const float* bk    = (const float*)d_in[7];
    const float* Wv    = (const float*)d_in[8];
    const float* Ww    = (const float*)d_in[9];
    const float* bw    = (const float*)d_in[10];
    float* out = (float*)d_out;

    const size_t per = (size_t)BW_ * H_ * L_ * HD_;  // 25,690,112 floats
    float* qp = (float*)d_ws;
    float* kp = qp + per;
    float* vp = kp + per;

    proj_kernel<<<dim3(BW_, 3), 256, 0, stream>>>(query, key_, value,
                                                  Wq, bq, Wk, bk, Wv,
                                                  qp, kp, vp);
    attn_kernel<<<dim3(BW_ * H_), 64, 0, stream>>>(qp, kp, vp, mask, qp);
    outproj_kernel<<<dim3(BW_), 256, 0, stream>>>(qp, Ww, bw, out);
}

// Round 2
// 544.843 us; speedup vs baseline: 1.9890x; 1.9890x over previous
//
#include <hip/hip_runtime.h>

#define B_    32
#define NW_   64
#define BW_   2048   // B*NW
#define L_    49
#define D_    192
#define PROJ_ 256
#define H_    8
#define HD_   32
#define BH_   (BW_ * H_)   // 16384

typedef __attribute__((ext_vector_type(8))) short bf16x8;
typedef __attribute__((ext_vector_type(4))) float f32x4;

__device__ __forceinline__ short f2bf(float f) {
    union { float f; unsigned u; } v; v.f = f;
    unsigned r = v.u + 0x7FFFu + ((v.u >> 16) & 1u);   // RNE
    return (short)(r >> 16);
}

// ---------------------------------------------------------------------------
// Weight prep: Wt[n][k] bf16 (k contiguous) = W[k][n], so MFMA B-fragments can
// be loaded directly from global as 16B/lane reads.
// grid (256, 4), block 256. y=0..2: Wq/Wk/Wv (192x256 -> 256x192).
// y=3: Ww (256x192 -> 192x256).
// ---------------------------------------------------------------------------
__global__ __launch_bounds__(256) void prep_weights(
    const float* __restrict__ Wq, const float* __restrict__ Wk,
    const float* __restrict__ Wv, const float* __restrict__ Ww,
    short* __restrict__ Wqt, short* __restrict__ Wkt,
    short* __restrict__ Wvt, short* __restrict__ Wwt)
{
    const int sel = blockIdx.y;
    const int n   = blockIdx.x;
    const int tid = threadIdx.x;
    if (sel < 3) {
        const float* src = (sel == 0) ? Wq : (sel == 1) ? Wk : Wv;
        short* dst = (sel == 0) ? Wqt : (sel == 1) ? Wkt : Wvt;
        if (tid < D_) dst[n * D_ + tid] = f2bf(src[tid * PROJ_ + n]);
    } else {
        if (n < D_) Wwt[n * PROJ_ + tid] = f2bf(Ww[tid * D_ + n]);
    }
}

// ---------------------------------------------------------------------------
// QKV projection, one block per window (2048 blocks, 256 threads = 4 waves).
// Wave w owns proj columns 64w..64w+63 (= heads 2w, 2w+1).
// X staged to LDS bf16 (rows 49..63 zeroed); B-frags straight from global Wt.
// Outputs (bf16, padded to 64 rows):
//   q_ws/k_ws: [bh][l:64][c:32]  (A / B frag layout for QK^T)
//   vT_ws:     [bh][c:32][l:64]  (B frag layout for PV)
// Padded rows evaluate to bias (q,k) or 0 (v) -> finite, safe downstream.
// ---------------------------------------------------------------------------
__global__ __launch_bounds__(256) void qkv_kernel(
    const float* __restrict__ query, const float* __restrict__ key_,
    const float* __restrict__ value,
    const short* __restrict__ Wqt, const short* __restrict__ Wkt,
    const short* __restrict__ Wvt,
    const float* __restrict__ bq, const float* __restrict__ bk,
    short* __restrict__ q_ws, short* __restrict__ k_ws,
    short* __restrict__ vT_ws)
{
    const int bw   = blockIdx.x;
    const int tid  = threadIdx.x;
    const int wave = tid >> 6;
    const int lane = tid & 63;
    const int m16  = lane & 15;
    const int quad = lane >> 4;
    const int cb   = wave * 64;

    __shared__ short Xb[64][200];   // pitch 200 bf16 = 400B: 16B-aligned frags, 2-way-max banks

    for (int sel = 0; sel < 3; ++sel) {
        const float* x  = (sel == 0) ? query : (sel == 1) ? key_ : value;
        const short* Wt = (sel == 0) ? Wqt : (sel == 1) ? Wkt : Wvt;

        __syncthreads();   // previous iteration's reads done before overwrite
        for (int i = tid; i < 64 * 48; i += 256) {
            int l = i / 48, c4 = i - l * 48;
            short4 s4;
            if (l < L_) {
                float4 v = *(const float4*)&x[((size_t)bw * L_ + l) * D_ + c4 * 4];
                s4.x = f2bf(v.x); s4.y = f2bf(v.y); s4.z = f2bf(v.z); s4.w = f2bf(v.w);
            } else {
                s4.x = 0; s4.y = 0; s4.z = 0; s4.w = 0;
            }
            *(short4*)&Xb[l][c4 * 4] = s4;
        }
        __syncthreads();

        f32x4 acc[4][4];
        #pragma unroll
        for (int mt = 0; mt < 4; ++mt)
            #pragma unroll
            for (int nt = 0; nt < 4; ++nt)
                acc[mt][nt] = (f32x4){0.f, 0.f, 0.f, 0.f};

        #pragma unroll
        for (int kc = 0; kc < 6; ++kc) {
            const int k0 = kc * 32;
            bf16x8 af[4], bf[4];
            #pragma unroll
            for (int mt = 0; mt < 4; ++mt)
                af[mt] = *(const bf16x8*)&Xb[mt * 16 + m16][k0 + quad * 8];
            #pragma unroll
            for (int nt = 0; nt < 4; ++nt) {
                const int n = cb + nt * 16 + m16;
                bf[nt] = *(const bf16x8*)&Wt[(size_t)n * D_ + k0 + quad * 8];
            }
            #pragma unroll
            for (int mt = 0; mt < 4; ++mt)
                #pragma unroll
                for (int nt = 0; nt < 4; ++nt)
                    acc[mt][nt] = __builtin_amdgcn_mfma_f32_16x16x32_bf16(
                        af[mt], bf[nt], acc[mt][nt], 0, 0, 0);
        }

        // epilogue: +bias, cvt bf16, scatter to head-split ws layouts
        #pragma unroll
        for (int nt = 0; nt < 4; ++nt) {
            const int col = cb + nt * 16 + m16;
            const int h = col >> 5, c = col & 31;
            float bias = 0.f;
            if (sel == 0) bias = bq[col];
            else if (sel == 1) bias = bk[col];
            #pragma unroll
            for (int mt = 0; mt < 4; ++mt)
                #pragma unroll
                for (int r = 0; r < 4; ++r) {
                    const int i = mt * 16 + quad * 4 + r;
                    const float v = acc[mt][nt][r] + bias;
                    if (sel == 2)
                        vT_ws[((size_t)(bw * H_ + h) * HD_ + c) * 64 + i] = f2bf(v);
                    else {
                        short* dst = (sel == 0) ? q_ws : k_ws;
                        dst[((size_t)(bw * H_ + h) * 64 + i) * HD_ + c] = f2bf(v);
                    }
                }
        }
    }
}

// ---------------------------------------------------------------------------
// Attention + output projection, one block per window (2048 blocks, 4 waves).
// Wave w does heads 2w, 2w+1 fully independently (q/k/v frags from global),
// softmax in-register via quad-group shuffles, P via per-wave LDS buffer
// (C-layout -> A-layout), O into shared LDS, then fused out-proj (K=256).
// ---------------------------------------------------------------------------
__global__ __launch_bounds__(256) void attn_out_kernel(
    const short* __restrict__ q_ws, const short* __restrict__ k_ws,
    const short* __restrict__ vT_ws, const int* __restrict__ mask,
    const short* __restrict__ Wwt, const float* __restrict__ bwb,
    float* __restrict__ out)
{
    const int bw   = blockIdx.x;
    const int w    = bw & (NW_ - 1);
    const int tid  = threadIdx.x;
    const int wave = tid >> 6;
    const int lane = tid & 63;
    const int m16  = lane & 15;
    const int quad = lane >> 4;

    __shared__ short Pb[4][64][72];   // per-wave P (A-layout source), 36.9KB
    __shared__ short Ob[64][264];     // attention output, all heads, 33.8KB

    const float scale = 0.17677669529663687f;  // 1/sqrt(32)

    #pragma unroll
    for (int hh = 0; hh < 2; ++hh) {
        const int head = wave * 2 + hh;
        const size_t bh = (size_t)bw * H_ + head;
        const short* qb = q_ws  + bh * (64 * HD_);
        const short* kb = k_ws  + bh * (64 * HD_);
        const short* vb = vT_ws + bh * (HD_ * 64);

        // ---- scores: S = q @ k^T, K=32 in one MFMA per tile ----
        f32x4 sacc[4][4];
        #pragma unroll
        for (int mt = 0; mt < 4; ++mt)
            #pragma unroll
            for (int nt = 0; nt < 4; ++nt)
                sacc[mt][nt] = (f32x4){0.f, 0.f, 0.f, 0.f};
        {
            bf16x8 af[4], bf[4];
            #pragma unroll
            for (int mt = 0; mt < 4; ++mt)
                af[mt] = *(const bf16x8*)&qb[(mt * 16 + m16) * HD_ + quad * 8];
            #pragma unroll
            for (int nt = 0; nt < 4; ++nt)
                bf[nt] = *(const bf16x8*)&kb[(nt * 16 + m16) * HD_ + quad * 8];
            #pragma unroll
            for (int mt = 0; mt < 4; ++mt)
                #pragma unroll
                for (int nt = 0; nt < 4; ++nt)
                    sacc[mt][nt] = __builtin_amdgcn_mfma_f32_16x16x32_bf16(
                        af[mt], bf[nt], sacc[mt][nt], 0, 0, 0);
        }

        // ---- mask + softmax (in-register, quad-group reduce) + P -> LDS ----
        #pragma unroll
        for (int mt = 0; mt < 4; ++mt) {
            #pragma unroll
            for (int r = 0; r < 4; ++r) {
                const int i = mt * 16 + quad * 4 + r;
                float s[4];
                #pragma unroll
                for (int nt = 0; nt < 4; ++nt) {
                    const int j = nt * 16 + m16;
                    float v = sacc[mt][nt][r] * scale;
                    if (j >= L_) v = -INFINITY;   // pad cols: excluded exactly
                    else if (i >= L_ || mask[w * (L_ * L_) + i * L_ + j] != 0)
                        v = -1000.0f;             // ref semantics (all-masked -> uniform)
                    s[nt] = v;
                }
                float mx = fmaxf(fmaxf(s[0], s[1]), fmaxf(s[2], s[3]));
                #pragma unroll
                for (int d = 1; d < 16; d <<= 1) mx = fmaxf(mx, __shfl_xor(mx, d, 64));
                float e[4], sum = 0.f;
                #pragma unroll
                for (int nt = 0; nt < 4; ++nt) { e[nt] = __expf(s[nt] - mx); sum += e[nt]; }
                #pragma unroll
                for (int d = 1; d < 16; d <<= 1) sum += __shfl_xor(sum, d, 64);
                const float inv = 1.0f / sum;
                #pragma unroll
                for (int nt = 0; nt < 4; ++nt)
                    Pb[wave][i][nt * 16 + m16] = f2bf(e[nt] * inv);
            }
        }

        // ---- O = P @ v : K=64 (2 chunks), N=32 (2 tiles) ----
        f32x4 oacc[4][2];
        #pragma unroll
        for (int mt = 0; mt < 4; ++mt)
            #pragma unroll
            for (int nt = 0; nt < 2; ++nt)
                oacc[mt][nt] = (f32x4){0.f, 0.f, 0.f, 0.f};
        #pragma unroll
        for (int kc = 0; kc < 2; ++kc) {
            const int j0 = kc * 32;
            bf16x8 pf[4], vf[2];
            #pragma unroll
            for (int mt = 0; mt < 4; ++mt)
                pf[mt] = *(const bf16x8*)&Pb[wave][mt * 16 + m16][j0 + quad * 8];
            #pragma unroll
            for (int nt = 0; nt < 2; ++nt)
                vf[nt] = *(const bf16x8*)&vb[(nt * 16 + m16) * 64 + j0 + quad * 8];
            #pragma unroll
            for (int mt = 0; mt < 4; ++mt)
                #pragma unroll
                for (int nt = 0; nt < 2; ++nt)
                    oacc[mt][nt] = __builtin_amdgcn_mfma_f32_16x16x32_bf16(
                        pf[mt], vf[nt], oacc[mt][nt], 0, 0, 0);
        }
        #pragma unroll
        for (int mt = 0; mt < 4; ++mt)
            #pragma unroll
            for (int nt = 0; nt < 2; ++nt)
                #pragma unroll
                for (int r = 0; r < 4; ++r)
                    Ob[mt * 16 + quad * 4 + r][head * HD_ + nt * 16 + m16] =
                        f2bf(oacc[mt][nt][r]);
    }

    __syncthreads();   // Ob complete across waves

    // ---- out = O @ Ww + bw : wave w owns cols 48w..48w+47, K=256 ----
    f32x4 cacc[4][3];
    #pragma unroll
    for (int mt = 0; mt < 4; ++mt)
        #pragma unroll
        for (int nt = 0; nt < 3; ++nt)
            cacc[mt][nt] = (f32x4){0.f, 0.f, 0.f, 0.f};
    #pragma unroll
    for (int kc = 0; kc < 8; ++kc) {
        const int k0 = kc * 32;
        bf16x8 af[4], bf[3];
        #pragma unroll
        for (int mt = 0; mt < 4; ++mt)
            af[mt] = *(const bf16x8*)&Ob[mt * 16 + m16][k0 + quad * 8];
        #pragma unroll
        for (int nt = 0; nt < 3; ++nt) {
            const int n = wave * 48 + nt * 16 + m16;
            bf[nt] = *(const bf16x8*)&Wwt[(size_t)n * PROJ_ + k0 + quad * 8];
        }
        #pragma unroll
        for (int mt = 0; mt < 4; ++mt)
            #pragma unroll
            for (int nt = 0; nt < 3; ++nt)
                cacc[mt][nt] = __builtin_amdgcn_mfma_f32_16x16x32_bf16(
                    af[mt], bf[nt], cacc[mt][nt], 0, 0, 0);
    }
    #pragma unroll
    for (int nt = 0; nt < 3; ++nt) {
        const int col = wave * 48 + nt * 16 + m16;
        const float bias = bwb[col];
        #pragma unroll
        for (int mt = 0; mt < 4; ++mt)
            #pragma unroll
            for (int r = 0; r < 4; ++r) {
                const int i = mt * 16 + quad * 4 + r;
                if (i < L_)
                    out[((size_t)bw * L_ + i) * D_ + col] = cacc[mt][nt][r] + bias;
            }
    }
}

extern "C" void kernel_launch(void* const* d_in, const int* in_sizes, int n_in,
                              void* d_out, int out_size, void* d_ws, size_t ws_size,
                              hipStream_t stream) {
    const float* query = (const float*)d_in[0];
    const float* key_  = (const float*)d_in[1];
    const float* value = (const float*)d_in[2];
    const int*   mask  = (const int*)d_in[3];
    const float* Wq    = (const float*)d_in[4];
    const float* bq    = (const float*)d_in[5];
    const float* Wk    = (const float*)d_in[6];
    const float* bk    = (const float*)d_in[7];
    const float* Wv    = (const float*)d_in[8];
    const float* Ww    = (const float*)d_in[9];
    const float* bw    = (const float*)d_in[10];
    float* out = (float*)d_out;

    const size_t per = (size_t)BH_ * 64 * HD_;   // 33,554,432 shorts per tensor
    short* q_ws  = (short*)d_ws;
    short* k_ws  = q_ws + per;
    short* vT_ws = k_ws + per;
    short* Wqt   = vT_ws + per;
    short* Wkt   = Wqt + D_ * PROJ_;
    short* Wvt   = Wkt + D_ * PROJ_;
    short* Wwt   = Wvt + D_ * PROJ_;

    prep_weights<<<dim3(256, 4), 256, 0, stream>>>(Wq, Wk, Wv, Ww, Wqt, Wkt, Wvt, Wwt);
    qkv_kernel<<<dim3(BW_), 256, 0, stream>>>(query, key_, value, Wqt, Wkt, Wvt,
                                              bq, bk, q_ws, k_ws, vT_ws);
    attn_out_kernel<<<dim3(BW_), 256, 0, stream>>>(q_ws, k_ws, vT_ws, mask, Wwt, bw, out);
}